// Round 7
// baseline (15566.531 us; speedup 1.0000x reference)
//
#include <hip/hip_runtime.h>
#include <cstdint>
#include <cstddef>

#define SEQ   8192
#define HD    2048
#define IND   16
#define NBLK  256   // one block per CU; each owns 8 hidden units
#define NTHR  256   // 4 waves; wave w owns units {b*8+2w, b*8+2w+1} = 8 rows
#define NSLOT 1024  // u64 slots per parity: lo32 = 2xfp16 h-pair, hi32 = tag
#define NXCD  8

// Gate: R14 showed 14 vs 24 ticks neutral -> T_vis ~850-1300cy; keep 16.
#define GATE_TICKS 16ull
#define TIGHT_TRIES 8

typedef _Float16 h2  __attribute__((ext_vector_type(2)));
typedef unsigned u32x4 __attribute__((ext_vector_type(4)));

union paircvt { h2 v; unsigned u; };

__device__ __forceinline__ float fdot2f(h2 a, h2 b, float c) {
#if defined(__has_builtin)
#if __has_builtin(__builtin_amdgcn_fdot2)
    return __builtin_amdgcn_fdot2(a, b, c, false);
#else
    return c + (float)a.x * (float)b.x + (float)a.y * (float)b.y;
#endif
#else
    return c + (float)a.x * (float)b.x + (float)a.y * (float)b.y;
#endif
}

__device__ __forceinline__ float sigmoid_f(float x) {
    return 1.f / (1.f + __expf(-x));
}
__device__ __forceinline__ float tanh_f(float x) {
    float e = __expf(2.f * x);
    return 1.f - 2.f / (e + 1.f);
}

__device__ __forceinline__ unsigned my_xcd() {
    unsigned x;
    asm volatile("s_getreg_b32 %0, hwreg(HW_REG_XCC_ID, 0, 4)" : "=s"(x));
    return x & (NXCD - 1);
}

// ---- VALU cross-lane primitives (replace DS-pipe shuffles) ----
__device__ __forceinline__ float dpp_xor1(float x) {
    int i = __builtin_bit_cast(int, x);
    int r = __builtin_amdgcn_mov_dpp(i, 0xB1, 0xf, 0xf, false); // [1,0,3,2]
    return __builtin_bit_cast(float, r);
}
__device__ __forceinline__ float dpp_xor2(float x) {
    int i = __builtin_bit_cast(int, x);
    int r = __builtin_amdgcn_mov_dpp(i, 0x4E, 0xf, 0xf, false); // [2,3,0,1]
    return __builtin_bit_cast(float, r);
}
__device__ __forceinline__ float xor16_add(float x) {
    float a = x, b = x;
    asm volatile("v_permlane16_swap_b32 %0, %1" : "+v"(a), "+v"(b));
    return a + b;
}
__device__ __forceinline__ float xor32_add(float x) {
    float a = x, b = x;
    asm volatile("v_permlane32_swap_b32 %0, %1" : "+v"(a), "+v"(b));
    return a + b;
}

// Persistent LSTM, round 16: per-lane DIRECT fetch, no LDS, no barrier.
// R15 left a serial movement chain after discovery: 4 ds_write ->
// lgkmcnt(0) -> block s_barrier (slowest thread in BLOCK gates all 4
// waves) -> 16 ds_read (~120cy first use). Lane L needs exactly slots
// [16L,16L+16) and the block poll already reads the whole 8KB region --
// so each lane now loads its own slice directly: the poll result IS
// hv[]. Waves decouple (slowest LANE in wave gates, not slowest thread
// in block).
// TRANSPOSED slot layout for coalescing: slot s (k=s&15, l=s>>4) stored
// at position (k>>1)*128 + 2l + (k&1). Lane L load j = dwordx4 at byte
// j*1024 + 16L: 8 fully-coalesced 1KB instructions cover the region.
// Producer writes one permuted position (loop-invariant) per replica.
// Parity-2 safety unchanged: tag t+3 can only be written after every
// wave has read tag t+1 (all-to-all distance-1 dependency).
// Compute arithmetic byte-identical to R13/14/15.
__global__ __launch_bounds__(NTHR, 1) void lstm_persist(
    const float* __restrict__ sa,    // [SEQ, IND]
    const float* __restrict__ W_ih,  // [4*HD, IND]
    const float* __restrict__ W_hh,  // [4*HD, HD]
    const float* __restrict__ b_ih,  // [4*HD]
    const float* __restrict__ b_hh,  // [4*HD]
    unsigned long long* __restrict__ hrep,  // [NXCD][2][NSLOT] replicas
    _Float16* __restrict__ hs16)     // [SEQ, HD] h history (fp16)
{
    const int b   = blockIdx.x;
    const int tid = threadIdx.x;
    const int w   = tid >> 6;        // wave 0..3
    const int L   = tid & 63;        // lane
    const unsigned xcd = my_xcd();

    const int ubase = b * 8 + 2 * w; // first of this wave's 2 units

    // ---- one-time: W_hh fragment -> registers (fp16 pairs) ----
    h2 wreg[8][16];
#pragma unroll
    for (int r = 0; r < 8; ++r) {
        const int row = (r & 3) * HD + ubase + (r >> 2);
        const float4* Wr = (const float4*)(W_hh + (size_t)row * HD + L * 32);
#pragma unroll
        for (int q = 0; q < 8; ++q) {
            float4 f = Wr[q];
            h2 lo; lo.x = (_Float16)f.x; lo.y = (_Float16)f.y;
            h2 hi; hi.x = (_Float16)f.z; hi.y = (_Float16)f.w;
            wreg[r][2 * q]     = lo;
            wreg[r][2 * q + 1] = hi;
        }
    }
    // W_ih row + bias for the row this lane ends up holding (r = L&7)
    const int rowL = (L & 3) * HD + ubase + ((L >> 2) & 1);
    float wih[IND];
    {
        const float4* Wi = (const float4*)(W_ih + (size_t)rowL * IND);
#pragma unroll
        for (int q = 0; q < 4; ++q) {
            float4 f = Wi[q];
            wih[4 * q]     = f.x;
            wih[4 * q + 1] = f.y;
            wih[4 * q + 2] = f.z;
            wih[4 * q + 3] = f.w;
        }
    }
    const float bias = b_ih[rowL] + b_hh[rowL];

    // ---- publish position in transposed layout (loop-invariant) ----
    const int slot = b * 4 + w;              // covers units 2s, 2s+1
    const int ppos = ((slot & 15) >> 1) * 128 + 2 * (slot >> 4) + (slot & 1);

    // x_t prefetch registers (depth 1)
    float sat[IND];
    {
        const float4* s4 = (const float4*)(sa);
#pragma unroll
        for (int q = 0; q < 4; ++q) {
            float4 f = s4[q];
            sat[4 * q]     = f.x;
            sat[4 * q + 1] = f.y;
            sat[4 * q + 2] = f.z;
            sat[4 * q + 3] = f.w;
        }
    }

    // cell state: lanes with (L&4)==0 hold c of unit0, (L&4)==4 -> unit1
    float c = 0.f;
    unsigned long long pubclk = 0;

    const unsigned voff0 = (unsigned)(L * 16);
    const unsigned voff1 = (unsigned)(L * 16 + 4096);

    for (unsigned t = 0; t < SEQ; ++t) {
        // ---- xp from prefetched x_t (no serial load stall) ----
        float xp = bias;
#pragma unroll
        for (int k = 0; k < IND; ++k) xp += sat[k] * wih[k];

        // ---- issue x_{t+1} prefetch PRE-GATE: retires under gate+poll ----
        if (t + 1 < SEQ) {
            const float4* s4 = (const float4*)(sa + (size_t)(t + 1) * IND);
#pragma unroll
            for (int q = 0; q < 4; ++q) {
                float4 f = s4[q];
                sat[4 * q]     = f.x;
                sat[4 * q + 1] = f.y;
                sat[4 * q + 2] = f.z;
                sat[4 * q + 3] = f.w;
            }
        }

        // ---- clock gate: no LLC polls before own-publish + min flight ----
        if (t) {
            unsigned long long now;
            do {
                now = __builtin_amdgcn_s_memrealtime();
            } while (now - pubclk < GATE_TICKS);
        }

        // ---- direct per-lane poll: 8 coalesced dwordx4 = own 16 slots ----
        const unsigned pin = t & 1;
        const unsigned long long baseaddr =
            (unsigned long long)(hrep + ((size_t)xcd * 2 + pin) * NSLOT);
        u32x4 m0, m1, m2, m3, m4, m5, m6, m7;
        int tries = 0;
        for (;;) {
            asm volatile(
                "global_load_dwordx4 %0, %8, %10 sc1\n\t"
                "global_load_dwordx4 %1, %8, %10 offset:1024 sc1\n\t"
                "global_load_dwordx4 %2, %8, %10 offset:2048 sc1\n\t"
                "global_load_dwordx4 %3, %8, %10 offset:3072 sc1\n\t"
                "global_load_dwordx4 %4, %9, %10 sc1\n\t"
                "global_load_dwordx4 %5, %9, %10 offset:1024 sc1\n\t"
                "global_load_dwordx4 %6, %9, %10 offset:2048 sc1\n\t"
                "global_load_dwordx4 %7, %9, %10 offset:3072 sc1\n\t"
                "s_waitcnt vmcnt(0)"
                : "=v"(m0), "=v"(m1), "=v"(m2), "=v"(m3),
                  "=v"(m4), "=v"(m5), "=v"(m6), "=v"(m7)
                : "v"(voff0), "v"(voff1), "s"(baseaddr)
                : "memory");
            bool ok = (m0.y == t) & (m0.w == t) & (m1.y == t) & (m1.w == t)
                    & (m2.y == t) & (m2.w == t) & (m3.y == t) & (m3.w == t)
                    & (m4.y == t) & (m4.w == t) & (m5.y == t) & (m5.w == t)
                    & (m6.y == t) & (m6.w == t) & (m7.y == t) & (m7.w == t);
            if (__all(ok)) break;
            if (++tries > TIGHT_TRIES) __builtin_amdgcn_s_sleep(1);
        }

        // ---- hv IS the poll payload: hv[2j]=m_j.x, hv[2j+1]=m_j.z ----
        h2 hv[16];
        {
            paircvt cv;
            cv.u = m0.x; hv[0]  = cv.v;  cv.u = m0.z; hv[1]  = cv.v;
            cv.u = m1.x; hv[2]  = cv.v;  cv.u = m1.z; hv[3]  = cv.v;
            cv.u = m2.x; hv[4]  = cv.v;  cv.u = m2.z; hv[5]  = cv.v;
            cv.u = m3.x; hv[6]  = cv.v;  cv.u = m3.z; hv[7]  = cv.v;
            cv.u = m4.x; hv[8]  = cv.v;  cv.u = m4.z; hv[9]  = cv.v;
            cv.u = m5.x; hv[10] = cv.v;  cv.u = m5.z; hv[11] = cv.v;
            cv.u = m6.x; hv[12] = cv.v;  cv.u = m6.z; hv[13] = cv.v;
            cv.u = m7.x; hv[14] = cv.v;  cv.u = m7.z; hv[15] = cv.v;
        }

        // ---- 8 rows x 32 cols of dot product per lane ----
        float p[8] = {0.f, 0.f, 0.f, 0.f, 0.f, 0.f, 0.f, 0.f};
#pragma unroll
        for (int r = 0; r < 8; ++r)
#pragma unroll
            for (int k = 0; k < 16; ++k)
                p[r] = fdot2f(wreg[r][k], hv[k], p[r]);

        // ---- merge-reduce: lane L ends with full sum of row (L&7) ----
        const bool h1 = (L & 1), h2b = (L & 2), h4 = (L & 4);
        float v0, v1, v2, v3;
        {
            float k0 = h1 ? p[1] : p[0], s0 = h1 ? p[0] : p[1];
            v0 = k0 + dpp_xor1(s0);
            float k1 = h1 ? p[3] : p[2], s1 = h1 ? p[2] : p[3];
            v1 = k1 + dpp_xor1(s1);
            float k2 = h1 ? p[5] : p[4], s2 = h1 ? p[4] : p[5];
            v2 = k2 + dpp_xor1(s2);
            float k3 = h1 ? p[7] : p[6], s3 = h1 ? p[6] : p[7];
            v3 = k3 + dpp_xor1(s3);
        }
        float w0, w1;
        {
            float k0 = h2b ? v1 : v0, s0 = h2b ? v0 : v1;
            w0 = k0 + dpp_xor2(s0);
            float k1 = h2b ? v3 : v2, s1 = h2b ? v2 : v3;
            w1 = k1 + dpp_xor2(s1);
        }
        float tot;
        {
            float k0 = h4 ? w1 : w0, s0 = h4 ? w0 : w1;
            tot = k0 + __shfl_xor(s0, 4, 64);
        }
        tot += __shfl_xor(tot, 8, 64);
        tot = xor16_add(tot);
        tot = xor32_add(tot);
        tot += xp;

        // ---- gates: all intra-wave (width-8 shuffles) ----
        const int ub4 = L & 4;   // 0 -> unit0 rows 0..3, 4 -> unit1 rows 4..7
        float gi = __shfl(tot, ub4 + 0, 8);
        float gf = __shfl(tot, ub4 + 1, 8);
        float gg = __shfl(tot, ub4 + 2, 8);
        float go = __shfl(tot, ub4 + 3, 8);
        float ii = sigmoid_f(gi);
        float ff = sigmoid_f(gf);
        float g  = tanh_f(gg);
        float oo = sigmoid_f(go);
        c = ff * c + ii * g;
        float h = oo * tanh_f(c);

        // ---- publish: two PARALLEL width-8 broadcasts, then lanes 0..7
        //      each store one replica (single predicated issue) ----
        {
            float hA = __shfl(h, 0, 8);   // unit ubase   (sublane 0)
            float hB = __shfl(h, 4, 8);   // unit ubase+1 (sublane 4)
            paircvt pk;
            pk.v.x = (_Float16)hA;
            pk.v.y = (_Float16)hB;
            const unsigned pout = (t + 1) & 1;
            unsigned long long msg =
                ((unsigned long long)(t + 1) << 32) | (unsigned long long)pk.u;
            if (L < 8)
                __hip_atomic_store(
                    &hrep[((size_t)L * 2 + pout) * NSLOT + ppos], msg,
                    __ATOMIC_RELAXED, __HIP_MEMORY_SCOPE_AGENT);
            // non-critical history write, off the publishing lanes
            if (L == 8)
                ((unsigned*)hs16)[(size_t)t * (HD / 2) + slot] = pk.u;
        }
        pubclk = __builtin_amdgcn_s_memrealtime();
    }
}

// Output projection: out[t,0:3] = hs[t]·W_uvw^T + b_uvw,
//                    out[t,3:6] = hs[t]·W_pqr^T + b_pqr
__global__ __launch_bounds__(256) void out_proj_kernel(
    const _Float16* __restrict__ hs16,
    const float* __restrict__ W_uvw, const float* __restrict__ b_uvw,
    const float* __restrict__ W_pqr, const float* __restrict__ b_pqr,
    float* __restrict__ out)
{
    __shared__ float Ws[6 * HD];
    const int tid = threadIdx.x;
    for (int i = tid; i < 3 * HD; i += 256) Ws[i] = W_uvw[i];
    for (int i = tid; i < 3 * HD; i += 256) Ws[3 * HD + i] = W_pqr[i];
    __syncthreads();

    const int w = tid >> 6, L = tid & 63;
#pragma unroll
    for (int r = 0; r < 4; ++r) {
        const int t = blockIdx.x * 16 + w * 4 + r;
        const _Float16* hrow = hs16 + (size_t)t * HD;
        float acc[6] = {0.f, 0.f, 0.f, 0.f, 0.f, 0.f};
        for (int cidx = L; cidx < HD; cidx += 64) {
            float hval = (float)hrow[cidx];
#pragma unroll
            for (int j = 0; j < 6; ++j) acc[j] += hval * Ws[j * HD + cidx];
        }
#pragma unroll
        for (int j = 0; j < 6; ++j) {
#pragma unroll
            for (int d = 1; d < 64; d <<= 1)
                acc[j] += __shfl_xor(acc[j], d, 64);
        }
        if (L == 0) {
#pragma unroll
            for (int j = 0; j < 6; ++j)
                out[(size_t)t * 6 + j] =
                    acc[j] + (j < 3 ? b_uvw[j] : b_pqr[j - 3]);
        }
    }
}

extern "C" void kernel_launch(void* const* d_in, const int* in_sizes, int n_in,
                              void* d_out, int out_size, void* d_ws, size_t ws_size,
                              hipStream_t stream) {
    (void)in_sizes; (void)n_in; (void)out_size; (void)ws_size;

    const float* sa    = (const float*)d_in[0];
    const float* W_ih  = (const float*)d_in[1];
    const float* W_hh  = (const float*)d_in[2];
    const float* b_ih  = (const float*)d_in[3];
    const float* b_hh  = (const float*)d_in[4];
    const float* W_uvw = (const float*)d_in[5];
    const float* b_uvw = (const float*)d_in[6];
    const float* W_pqr = (const float*)d_in[7];
    const float* b_pqr = (const float*)d_in[8];
    float* out = (float*)d_out;

    // workspace: [hs16: 32 MB][hrep: NXCD*2*NSLOT*8 = 128 KB]
    char* ws = (char*)d_ws;
    _Float16* hs16 = (_Float16*)ws;
    unsigned long long* hrep =
        (unsigned long long*)(ws + (size_t)SEQ * HD * 2);

    // zero replicas: tag 0 == "h_0 = 0 is ready" in every copy
    hipMemsetAsync(hrep, 0, (size_t)NXCD * 2 * NSLOT * 8, stream);

    hipLaunchKernelGGL(lstm_persist, dim3(NBLK), dim3(NTHR), 0, stream,
                       sa, W_ih, W_hh, b_ih, b_hh, hrep, hs16);
    hipLaunchKernelGGL(out_proj_kernel, dim3(SEQ / 16), dim3(256), 0, stream,
                       hs16, W_uvw, b_uvw, W_pqr, b_pqr, out);
}

// Round 8
// 14325.026 us; speedup vs baseline: 1.0867x; 1.0867x over previous
//
#include <hip/hip_runtime.h>
#include <cstdint>
#include <cstddef>

#define SEQ   8192
#define HD    2048
#define IND   16
#define NBLK  256   // one block per CU; each owns 8 hidden units
#define NTHR  256   // 4 waves; wave w owns units {b*8+2w, b*8+2w+1} = 8 rows
#define NSLOT 1024  // u64 slots per parity: lo32 = 2xfp16 h-pair, hi32 = tag
#define NXCD  8

// Gate: R14 showed 14 vs 24 ticks neutral -> T_vis ~850-1300cy; keep 16.
#define GATE_TICKS 16ull

typedef _Float16 h2  __attribute__((ext_vector_type(2)));
typedef unsigned u32x4 __attribute__((ext_vector_type(4)));

union paircvt { h2 v; unsigned u; };

__device__ __forceinline__ float fdot2f(h2 a, h2 b, float c) {
#if defined(__has_builtin)
#if __has_builtin(__builtin_amdgcn_fdot2)
    return __builtin_amdgcn_fdot2(a, b, c, false);
#else
    return c + (float)a.x * (float)b.x + (float)a.y * (float)b.y;
#endif
#else
    return c + (float)a.x * (float)b.x + (float)a.y * (float)b.y;
#endif
}

__device__ __forceinline__ float sigmoid_f(float x) {
    return 1.f / (1.f + __expf(-x));
}
__device__ __forceinline__ float tanh_f(float x) {
    float e = __expf(2.f * x);
    return 1.f - 2.f / (e + 1.f);
}

__device__ __forceinline__ unsigned my_xcd() {
    unsigned x;
    asm volatile("s_getreg_b32 %0, hwreg(HW_REG_XCC_ID, 0, 4)" : "=s"(x));
    return x & (NXCD - 1);
}

// ---- VALU cross-lane primitives (replace DS-pipe shuffles) ----
__device__ __forceinline__ float dpp_xor1(float x) {
    int i = __builtin_bit_cast(int, x);
    int r = __builtin_amdgcn_mov_dpp(i, 0xB1, 0xf, 0xf, false); // [1,0,3,2]
    return __builtin_bit_cast(float, r);
}
__device__ __forceinline__ float dpp_xor2(float x) {
    int i = __builtin_bit_cast(int, x);
    int r = __builtin_amdgcn_mov_dpp(i, 0x4E, 0xf, 0xf, false); // [2,3,0,1]
    return __builtin_bit_cast(float, r);
}
// row_ror:8 (ctrl 0x128): within each 16-lane row, dest L reads (L+8)&15,
// which equals L^8 -- an exact xor-8 butterfly on the VALU pipe.
__device__ __forceinline__ float dpp_ror8(float x) {
    int i = __builtin_bit_cast(int, x);
    int r = __builtin_amdgcn_mov_dpp(i, 0x128, 0xf, 0xf, false);
    return __builtin_bit_cast(float, r);
}
__device__ __forceinline__ float xor16_add(float x) {
    float a = x, b = x;
    asm volatile("v_permlane16_swap_b32 %0, %1" : "+v"(a), "+v"(b));
    return a + b;
}
__device__ __forceinline__ float xor32_add(float x) {
    float a = x, b = x;
    asm volatile("v_permlane32_swap_b32 %0, %1" : "+v"(a), "+v"(b));
    return a + b;
}

// Persistent LSTM, round 17: revert R16 (direct fetch: 4x poll traffic,
// all-or-nothing retries -> +1.5ms) back to the R15 structure, plus ONE
// tail trim: merge-reduce dimensions reordered {1,2,4}->{1,2,8} so the
// third MERGE rides DPP row_ror:8 (VALU) and only the d=4 pure reduction
// stays on DS. Serial DS waits in the reduce: 3 -> 2 (~40cy/step).
// New row->lane map: lane L holds row (L&3) | ((L&8)>>1), i.e. gate=L&3,
// unit=(L&8)>>3. Adjusted accordingly: xp row select (L>>3 instead of
// L>>2), gate gather (width-16 shuffles from lanes (L&8)+r), h broadcast
// (shfl 0/8 width 16), c carried per-lane for unit (L&8)>>3.
// Same summands, different association order -> absmax class unchanged.
// All else byte-identical to R15 (staggered poll, raw lgkm-only barrier,
// gate=16, pre-gate sat prefetch, lane-spread publish).
__global__ __launch_bounds__(NTHR, 1) void lstm_persist(
    const float* __restrict__ sa,    // [SEQ, IND]
    const float* __restrict__ W_ih,  // [4*HD, IND]
    const float* __restrict__ W_hh,  // [4*HD, HD]
    const float* __restrict__ b_ih,  // [4*HD]
    const float* __restrict__ b_hh,  // [4*HD]
    unsigned long long* __restrict__ hrep,  // [NXCD][2][NSLOT] replicas
    _Float16* __restrict__ hs16)     // [SEQ, HD] h history (fp16)
{
    const int b   = blockIdx.x;
    const int tid = threadIdx.x;
    const int w   = tid >> 6;        // wave 0..3
    const int L   = tid & 63;        // lane
    const unsigned xcd = my_xcd();

    __shared__ h2 hh2[16 * 64];      // h_t pairs, XOR-swizzled [k][row^2k]

    const int ubase = b * 8 + 2 * w; // first of this wave's 2 units

    // ---- one-time: W_hh fragment -> registers (fp16 pairs) ----
    h2 wreg[8][16];
#pragma unroll
    for (int r = 0; r < 8; ++r) {
        const int row = (r & 3) * HD + ubase + (r >> 2);
        const float4* Wr = (const float4*)(W_hh + (size_t)row * HD + L * 32);
#pragma unroll
        for (int q = 0; q < 8; ++q) {
            float4 f = Wr[q];
            h2 lo; lo.x = (_Float16)f.x; lo.y = (_Float16)f.y;
            h2 hi; hi.x = (_Float16)f.z; hi.y = (_Float16)f.w;
            wreg[r][2 * q]     = lo;
            wreg[r][2 * q + 1] = hi;
        }
    }
    // W_ih row + bias for the row this lane ends up holding:
    // NEW map: gate = L&3, unit = (L>>3)&1 (bit3, was bit2)
    const int rowL = (L & 3) * HD + ubase + ((L >> 3) & 1);
    float wih[IND];
    {
        const float4* Wi = (const float4*)(W_ih + (size_t)rowL * IND);
#pragma unroll
        for (int q = 0; q < 4; ++q) {
            float4 f = Wi[q];
            wih[4 * q]     = f.x;
            wih[4 * q + 1] = f.y;
            wih[4 * q + 2] = f.z;
            wih[4 * q + 3] = f.w;
        }
    }
    const float bias = b_ih[rowL] + b_hh[rowL];

    // ---- hoisted LDS addresses (loop-invariant swizzle math) ----
    h2* wp0; h2* wp1; h2* wp2; h2* wp3;
    {
        const int pa = 2 * tid, pb = 2 * tid + 1;
        const int pc = 512 + 2 * tid, pd = 513 + 2 * tid;
        wp0 = &hh2[(pa & 15) * 64 + (((pa >> 4) ^ (2 * (pa & 15))) & 63)];
        wp1 = &hh2[(pb & 15) * 64 + (((pb >> 4) ^ (2 * (pb & 15))) & 63)];
        wp2 = &hh2[(pc & 15) * 64 + (((pc >> 4) ^ (2 * (pc & 15))) & 63)];
        wp3 = &hh2[(pd & 15) * 64 + (((pd >> 4) ^ (2 * (pd & 15))) & 63)];
    }
    const h2* rp[16];
#pragma unroll
    for (int k = 0; k < 16; ++k)
        rp[k] = &hh2[k * 64 + ((L ^ (2 * k)) & 63)];

    // x_t prefetch registers (depth 1)
    float sat[IND];
    {
        const float4* s4 = (const float4*)(sa);
#pragma unroll
        for (int q = 0; q < 4; ++q) {
            float4 f = s4[q];
            sat[4 * q]     = f.x;
            sat[4 * q + 1] = f.y;
            sat[4 * q + 2] = f.z;
            sat[4 * q + 3] = f.w;
        }
    }

    // cell state: lanes with (L&8)==0 hold c of unit0, (L&8)==8 -> unit1
    float c = 0.f;
    unsigned long long pubclk = 0;

    for (unsigned t = 0; t < SEQ; ++t) {
        // ---- xp from prefetched x_t (no serial load stall) ----
        float xp = bias;
#pragma unroll
        for (int k = 0; k < IND; ++k) xp += sat[k] * wih[k];

        // ---- issue x_{t+1} prefetch PRE-GATE: retires under gate+poll ----
        if (t + 1 < SEQ) {
            const float4* s4 = (const float4*)(sa + (size_t)(t + 1) * IND);
#pragma unroll
            for (int q = 0; q < 4; ++q) {
                float4 f = s4[q];
                sat[4 * q]     = f.x;
                sat[4 * q + 1] = f.y;
                sat[4 * q + 2] = f.z;
                sat[4 * q + 3] = f.w;
            }
        }

        // ---- clock gate: no LLC polls before own-publish + min flight ----
        if (t) {
            unsigned long long now;
            do {
                now = __builtin_amdgcn_s_memrealtime();
            } while (now - pubclk < GATE_TICKS);
        }

        // ---- staggered double-buffered poll of own-XCD replica ----
        const unsigned pin = t & 1;
        const uint32_t* base =
            (const uint32_t*)(hrep + ((size_t)xcd * 2 + pin) * NSLOT);
        const uint32_t* pp0 = base + 4 * tid;
        const uint32_t* pp1 = base + 1024 + 4 * tid;
        u32x4 m0, m1, n0, n1;
        asm volatile("s_waitcnt vmcnt(0)" ::: "memory");
        asm volatile(
            "global_load_dwordx4 %0, %2, off sc1\n\t"
            "global_load_dwordx4 %1, %3, off sc1"
            : "=v"(m0), "=v"(m1) : "v"(pp0), "v"(pp1) : "memory");
        int tries = 0;
        for (;;) {
            asm volatile(
                "global_load_dwordx4 %0, %2, off sc1\n\t"
                "global_load_dwordx4 %1, %3, off sc1"
                : "=v"(n0), "=v"(n1) : "v"(pp0), "v"(pp1) : "memory");
            asm volatile("s_waitcnt vmcnt(2)"
                         : "+v"(m0), "+v"(m1) :: "memory");
            if ((m0.y == t) & (m0.w == t) & (m1.y == t) & (m1.w == t))
                break;
            asm volatile(
                "global_load_dwordx4 %0, %2, off sc1\n\t"
                "global_load_dwordx4 %1, %3, off sc1"
                : "=v"(m0), "=v"(m1) : "v"(pp0), "v"(pp1) : "memory");
            asm volatile("s_waitcnt vmcnt(2)"
                         : "+v"(n0), "+v"(n1) :: "memory");
            if ((n0.y == t) & (n0.w == t) & (n1.y == t) & (n1.w == t)) {
                m0 = n0; m1 = n1;
                break;
            }
            if (++tries > 8) __builtin_amdgcn_s_sleep(1);
        }

        // ---- stage 4 pairs into swizzled LDS (<=2-way = free) ----
        {
            paircvt cv;
            cv.u = m0.x; *wp0 = cv.v;
            cv.u = m0.z; *wp1 = cv.v;
            cv.u = m1.x; *wp2 = cv.v;
            cv.u = m1.z; *wp3 = cv.v;
        }
        // RAW barrier: order only the LDS staging (lgkmcnt), NOT vmcnt --
        // stale staggered poll loads retire under the dots.
        asm volatile("s_waitcnt lgkmcnt(0)" ::: "memory");
        __builtin_amdgcn_s_barrier();

        // ---- read this lane's 16 pairs (cols [32L, 32L+32)) ----
        h2 hv[16];
#pragma unroll
        for (int k = 0; k < 16; ++k)
            hv[k] = *rp[k];

        // ---- 8 rows x 32 cols of dot product per lane ----
        float p[8] = {0.f, 0.f, 0.f, 0.f, 0.f, 0.f, 0.f, 0.f};
#pragma unroll
        for (int r = 0; r < 8; ++r)
#pragma unroll
            for (int k = 0; k < 16; ++k)
                p[r] = fdot2f(wreg[r][k], hv[k], p[r]);

        // ---- merge-reduce, dims {1,2,8} on VALU; d=4 pure-reduce on DS ----
        // lane L ends holding row (L&3)|((L&8)>>1): gate=L&3, unit=(L&8)>>3
        const bool h1 = (L & 1), h2b = (L & 2), h8 = (L & 8);
        float v0, v1, v2, v3;
        {
            float k0 = h1 ? p[1] : p[0], s0 = h1 ? p[0] : p[1];
            v0 = k0 + dpp_xor1(s0);
            float k1 = h1 ? p[3] : p[2], s1 = h1 ? p[2] : p[3];
            v1 = k1 + dpp_xor1(s1);
            float k2 = h1 ? p[5] : p[4], s2 = h1 ? p[4] : p[5];
            v2 = k2 + dpp_xor1(s2);
            float k3 = h1 ? p[7] : p[6], s3 = h1 ? p[6] : p[7];
            v3 = k3 + dpp_xor1(s3);
        }
        float w0, w1;
        {
            float k0 = h2b ? v1 : v0, s0 = h2b ? v0 : v1;
            w0 = k0 + dpp_xor2(s0);
            float k1 = h2b ? v3 : v2, s1 = h2b ? v2 : v3;
            w1 = k1 + dpp_xor2(s1);
        }
        float tot;
        {
            float k0 = h8 ? w1 : w0, s0 = h8 ? w0 : w1;
            tot = k0 + dpp_ror8(s0);          // d=8 merge on VALU
        }
        tot += __shfl_xor(tot, 4, 64);        // d=4 pure reduction (DS)
        tot = xor16_add(tot);
        tot = xor32_add(tot);
        tot += xp;

        // ---- gates: width-16 gathers from lanes {(L&8)+r} ----
        const int ub8 = L & 8;   // 0 -> unit0 rows on lanes 0..3, 8 -> unit1
        float gi = __shfl(tot, ub8 + 0, 16);
        float gf = __shfl(tot, ub8 + 1, 16);
        float gg = __shfl(tot, ub8 + 2, 16);
        float go = __shfl(tot, ub8 + 3, 16);
        float ii = sigmoid_f(gi);
        float ff = sigmoid_f(gf);
        float g  = tanh_f(gg);
        float oo = sigmoid_f(go);
        c = ff * c + ii * g;
        float h = oo * tanh_f(c);

        // ---- publish: two PARALLEL width-16 broadcasts, then lanes 0..7
        //      each store one replica (single predicated issue) ----
        {
            float hA = __shfl(h, 0, 16);  // unit ubase   (sublane 0)
            float hB = __shfl(h, 8, 16);  // unit ubase+1 (sublane 8)
            paircvt pk;
            pk.v.x = (_Float16)hA;
            pk.v.y = (_Float16)hB;
            const unsigned pout = (t + 1) & 1;
            const size_t slot = (size_t)b * 4 + w;
            unsigned long long msg =
                ((unsigned long long)(t + 1) << 32) | (unsigned long long)pk.u;
            if (L < 8)
                __hip_atomic_store(
                    &hrep[((size_t)L * 2 + pout) * NSLOT + slot], msg,
                    __ATOMIC_RELAXED, __HIP_MEMORY_SCOPE_AGENT);
            // non-critical history write, off the publishing lanes
            if (L == 16)
                ((unsigned*)hs16)[(size_t)t * (HD / 2) + b * 4 + w] = pk.u;
        }
        pubclk = __builtin_amdgcn_s_memrealtime();
    }
}

// Output projection: out[t,0:3] = hs[t]·W_uvw^T + b_uvw,
//                    out[t,3:6] = hs[t]·W_pqr^T + b_pqr
__global__ __launch_bounds__(256) void out_proj_kernel(
    const _Float16* __restrict__ hs16,
    const float* __restrict__ W_uvw, const float* __restrict__ b_uvw,
    const float* __restrict__ W_pqr, const float* __restrict__ b_pqr,
    float* __restrict__ out)
{
    __shared__ float Ws[6 * HD];
    const int tid = threadIdx.x;
    for (int i = tid; i < 3 * HD; i += 256) Ws[i] = W_uvw[i];
    for (int i = tid; i < 3 * HD; i += 256) Ws[3 * HD + i] = W_pqr[i];
    __syncthreads();

    const int w = tid >> 6, L = tid & 63;
#pragma unroll
    for (int r = 0; r < 4; ++r) {
        const int t = blockIdx.x * 16 + w * 4 + r;
        const _Float16* hrow = hs16 + (size_t)t * HD;
        float acc[6] = {0.f, 0.f, 0.f, 0.f, 0.f, 0.f};
        for (int cidx = L; cidx < HD; cidx += 64) {
            float hval = (float)hrow[cidx];
#pragma unroll
            for (int j = 0; j < 6; ++j) acc[j] += hval * Ws[j * HD + cidx];
        }
#pragma unroll
        for (int j = 0; j < 6; ++j) {
#pragma unroll
            for (int d = 1; d < 64; d <<= 1)
                acc[j] += __shfl_xor(acc[j], d, 64);
        }
        if (L == 0) {
#pragma unroll
            for (int j = 0; j < 6; ++j)
                out[(size_t)t * 6 + j] =
                    acc[j] + (j < 3 ? b_uvw[j] : b_pqr[j - 3]);
        }
    }
}

extern "C" void kernel_launch(void* const* d_in, const int* in_sizes, int n_in,
                              void* d_out, int out_size, void* d_ws, size_t ws_size,
                              hipStream_t stream) {
    (void)in_sizes; (void)n_in; (void)out_size; (void)ws_size;

    const float* sa    = (const float*)d_in[0];
    const float* W_ih  = (const float*)d_in[1];
    const float* W_hh  = (const float*)d_in[2];
    const float* b_ih  = (const float*)d_in[3];
    const float* b_hh  = (const float*)d_in[4];
    const float* W_uvw = (const float*)d_in[5];
    const float* b_uvw = (const float*)d_in[6];
    const float* W_pqr = (const float*)d_in[7];
    const float* b_pqr = (const float*)d_in[8];
    float* out = (float*)d_out;

    // workspace: [hs16: 32 MB][hrep: NXCD*2*NSLOT*8 = 128 KB]
    char* ws = (char*)d_ws;
    _Float16* hs16 = (_Float16*)ws;
    unsigned long long* hrep =
        (unsigned long long*)(ws + (size_t)SEQ * HD * 2);

    // zero replicas: tag 0 == "h_0 = 0 is ready" in every copy
    hipMemsetAsync(hrep, 0, (size_t)NXCD * 2 * NSLOT * 8, stream);

    hipLaunchKernelGGL(lstm_persist, dim3(NBLK), dim3(NTHR), 0, stream,
                       sa, W_ih, W_hh, b_ih, b_hh, hrep, hs16);
    hipLaunchKernelGGL(out_proj_kernel, dim3(SEQ / 16), dim3(256), 0, stream,
                       hs16, W_uvw, b_uvw, W_pqr, b_pqr, out);
}

// Round 9
// 13706.296 us; speedup vs baseline: 1.1357x; 1.0451x over previous
//
#include <hip/hip_runtime.h>
#include <cstdint>
#include <cstddef>

#define SEQ   8192
#define HD    2048
#define IND   16
#define NBLK  256   // one block per CU; each owns 8 hidden units
#define NTHR  256   // 4 waves; wave w owns units {b*8+2w, b*8+2w+1} = 8 rows
#define NSLOT 1024  // u64 slots per parity: lo32 = 2xfp16 h-pair, hi32 = tag
#define NXCD  8

// Gate: R14 showed 14 vs 24 ticks neutral -> T_vis ~850-1300cy; keep 16.
#define GATE_TICKS 16ull

typedef _Float16 h2  __attribute__((ext_vector_type(2)));
typedef unsigned u32x4 __attribute__((ext_vector_type(4)));

union paircvt { h2 v; unsigned u; };

__device__ __forceinline__ float fdot2f(h2 a, h2 b, float c) {
#if defined(__has_builtin)
#if __has_builtin(__builtin_amdgcn_fdot2)
    return __builtin_amdgcn_fdot2(a, b, c, false);
#else
    return c + (float)a.x * (float)b.x + (float)a.y * (float)b.y;
#endif
#else
    return c + (float)a.x * (float)b.x + (float)a.y * (float)b.y;
#endif
}

__device__ __forceinline__ float sigmoid_f(float x) {
    return 1.f / (1.f + __expf(-x));
}
__device__ __forceinline__ float tanh_f(float x) {
    float e = __expf(2.f * x);
    return 1.f - 2.f / (e + 1.f);
}

__device__ __forceinline__ unsigned my_xcd() {
    unsigned x;
    asm volatile("s_getreg_b32 %0, hwreg(HW_REG_XCC_ID, 0, 4)" : "=s"(x));
    return x & (NXCD - 1);
}

// ---- VALU cross-lane primitives (replace DS-pipe shuffles) ----
__device__ __forceinline__ float dpp_xor1(float x) {
    int i = __builtin_bit_cast(int, x);
    int r = __builtin_amdgcn_mov_dpp(i, 0xB1, 0xf, 0xf, false); // [1,0,3,2]
    return __builtin_bit_cast(float, r);
}
__device__ __forceinline__ float dpp_xor2(float x) {
    int i = __builtin_bit_cast(int, x);
    int r = __builtin_amdgcn_mov_dpp(i, 0x4E, 0xf, 0xf, false); // [2,3,0,1]
    return __builtin_bit_cast(float, r);
}
// row_ror:8 (ctrl 0x128): within each 16-lane row, dest L reads (L+8)&15,
// which equals L^8 -- an exact xor-8 butterfly on the VALU pipe.
__device__ __forceinline__ float dpp_ror8(float x) {
    int i = __builtin_bit_cast(int, x);
    int r = __builtin_amdgcn_mov_dpp(i, 0x128, 0xf, 0xf, false);
    return __builtin_bit_cast(float, r);
}
__device__ __forceinline__ float xor16_add(float x) {
    float a = x, b = x;
    asm volatile("v_permlane16_swap_b32 %0, %1" : "+v"(a), "+v"(b));
    return a + b;
}
__device__ __forceinline__ float xor32_add(float x) {
    float a = x, b = x;
    asm volatile("v_permlane32_swap_b32 %0, %1" : "+v"(a), "+v"(b));
    return a + b;
}

// Persistent LSTM, round 18: per-block COALESCED publish.
// Post-R17 triangulation: consumer sampling (R15, +1.4%), compute tail
// (R13/R17, hidden), gate (R14, neutral) -> the unexplained ~1700cy/step
// lives on the PRODUCER store path. Audit: hrep slots are contiguous 8B,
// so each 64B LLC line receives 8 stores from 8 DIFFERENT waves per step
// (8192 stores bursting into 1024 lines within ~200cy) -> per-line RMW
// serialization at the memory-side LLC inflates effective T_vis.
// Fix: the 4 waves deposit msg u64 into LDS pkbuf[4]; second raw barrier
// (lgkm-only); wave 0 lanes 0..31 store ALL 4 block-slots x 8 replicas in
// ONE instruction (lane λ -> replica λ>>2, slot b*4+(λ&3)): 4 adjacent
// lanes per replica = contiguous 32B = hardware-coalesced single
// transaction. Store transactions 8192 -> 2048/step; writers per line
// 8 -> 2. Waves 1-3 skip publish and run ahead; wave 1 lanes 0..3 write
// the hs16 history (coalesced 16B). Poll/compute byte-identical to R17.
__global__ __launch_bounds__(NTHR, 1) void lstm_persist(
    const float* __restrict__ sa,    // [SEQ, IND]
    const float* __restrict__ W_ih,  // [4*HD, IND]
    const float* __restrict__ W_hh,  // [4*HD, HD]
    const float* __restrict__ b_ih,  // [4*HD]
    const float* __restrict__ b_hh,  // [4*HD]
    unsigned long long* __restrict__ hrep,  // [NXCD][2][NSLOT] replicas
    _Float16* __restrict__ hs16)     // [SEQ, HD] h history (fp16)
{
    const int b   = blockIdx.x;
    const int tid = threadIdx.x;
    const int w   = tid >> 6;        // wave 0..3
    const int L   = tid & 63;        // lane
    const unsigned xcd = my_xcd();

    __shared__ h2 hh2[16 * 64];      // h_t pairs, XOR-swizzled [k][row^2k]
    __shared__ unsigned long long pkbuf[4];   // per-wave packed messages

    const int ubase = b * 8 + 2 * w; // first of this wave's 2 units

    // ---- one-time: W_hh fragment -> registers (fp16 pairs) ----
    h2 wreg[8][16];
#pragma unroll
    for (int r = 0; r < 8; ++r) {
        const int row = (r & 3) * HD + ubase + (r >> 2);
        const float4* Wr = (const float4*)(W_hh + (size_t)row * HD + L * 32);
#pragma unroll
        for (int q = 0; q < 8; ++q) {
            float4 f = Wr[q];
            h2 lo; lo.x = (_Float16)f.x; lo.y = (_Float16)f.y;
            h2 hi; hi.x = (_Float16)f.z; hi.y = (_Float16)f.w;
            wreg[r][2 * q]     = lo;
            wreg[r][2 * q + 1] = hi;
        }
    }
    // W_ih row + bias; row map (R17): gate = L&3, unit = (L>>3)&1
    const int rowL = (L & 3) * HD + ubase + ((L >> 3) & 1);
    float wih[IND];
    {
        const float4* Wi = (const float4*)(W_ih + (size_t)rowL * IND);
#pragma unroll
        for (int q = 0; q < 4; ++q) {
            float4 f = Wi[q];
            wih[4 * q]     = f.x;
            wih[4 * q + 1] = f.y;
            wih[4 * q + 2] = f.z;
            wih[4 * q + 3] = f.w;
        }
    }
    const float bias = b_ih[rowL] + b_hh[rowL];

    // ---- hoisted LDS addresses (loop-invariant swizzle math) ----
    h2* wp0; h2* wp1; h2* wp2; h2* wp3;
    {
        const int pa = 2 * tid, pb = 2 * tid + 1;
        const int pc = 512 + 2 * tid, pd = 513 + 2 * tid;
        wp0 = &hh2[(pa & 15) * 64 + (((pa >> 4) ^ (2 * (pa & 15))) & 63)];
        wp1 = &hh2[(pb & 15) * 64 + (((pb >> 4) ^ (2 * (pb & 15))) & 63)];
        wp2 = &hh2[(pc & 15) * 64 + (((pc >> 4) ^ (2 * (pc & 15))) & 63)];
        wp3 = &hh2[(pd & 15) * 64 + (((pd >> 4) ^ (2 * (pd & 15))) & 63)];
    }
    const h2* rp[16];
#pragma unroll
    for (int k = 0; k < 16; ++k)
        rp[k] = &hh2[k * 64 + ((L ^ (2 * k)) & 63)];

    // x_t prefetch registers (depth 1)
    float sat[IND];
    {
        const float4* s4 = (const float4*)(sa);
#pragma unroll
        for (int q = 0; q < 4; ++q) {
            float4 f = s4[q];
            sat[4 * q]     = f.x;
            sat[4 * q + 1] = f.y;
            sat[4 * q + 2] = f.z;
            sat[4 * q + 3] = f.w;
        }
    }

    // cell state: lanes with (L&8)==0 hold c of unit0, (L&8)==8 -> unit1
    float c = 0.f;
    unsigned long long pubclk = 0;

    for (unsigned t = 0; t < SEQ; ++t) {
        // ---- xp from prefetched x_t (no serial load stall) ----
        float xp = bias;
#pragma unroll
        for (int k = 0; k < IND; ++k) xp += sat[k] * wih[k];

        // ---- issue x_{t+1} prefetch PRE-GATE: retires under gate+poll ----
        if (t + 1 < SEQ) {
            const float4* s4 = (const float4*)(sa + (size_t)(t + 1) * IND);
#pragma unroll
            for (int q = 0; q < 4; ++q) {
                float4 f = s4[q];
                sat[4 * q]     = f.x;
                sat[4 * q + 1] = f.y;
                sat[4 * q + 2] = f.z;
                sat[4 * q + 3] = f.w;
            }
        }

        // ---- clock gate: no LLC polls before own-publish + min flight ----
        if (t) {
            unsigned long long now;
            do {
                now = __builtin_amdgcn_s_memrealtime();
            } while (now - pubclk < GATE_TICKS);
        }

        // ---- staggered double-buffered poll of own-XCD replica ----
        const unsigned pin = t & 1;
        const uint32_t* base =
            (const uint32_t*)(hrep + ((size_t)xcd * 2 + pin) * NSLOT);
        const uint32_t* pp0 = base + 4 * tid;
        const uint32_t* pp1 = base + 1024 + 4 * tid;
        u32x4 m0, m1, n0, n1;
        asm volatile("s_waitcnt vmcnt(0)" ::: "memory");
        asm volatile(
            "global_load_dwordx4 %0, %2, off sc1\n\t"
            "global_load_dwordx4 %1, %3, off sc1"
            : "=v"(m0), "=v"(m1) : "v"(pp0), "v"(pp1) : "memory");
        int tries = 0;
        for (;;) {
            asm volatile(
                "global_load_dwordx4 %0, %2, off sc1\n\t"
                "global_load_dwordx4 %1, %3, off sc1"
                : "=v"(n0), "=v"(n1) : "v"(pp0), "v"(pp1) : "memory");
            asm volatile("s_waitcnt vmcnt(2)"
                         : "+v"(m0), "+v"(m1) :: "memory");
            if ((m0.y == t) & (m0.w == t) & (m1.y == t) & (m1.w == t))
                break;
            asm volatile(
                "global_load_dwordx4 %0, %2, off sc1\n\t"
                "global_load_dwordx4 %1, %3, off sc1"
                : "=v"(m0), "=v"(m1) : "v"(pp0), "v"(pp1) : "memory");
            asm volatile("s_waitcnt vmcnt(2)"
                         : "+v"(n0), "+v"(n1) :: "memory");
            if ((n0.y == t) & (n0.w == t) & (n1.y == t) & (n1.w == t)) {
                m0 = n0; m1 = n1;
                break;
            }
            if (++tries > 8) __builtin_amdgcn_s_sleep(1);
        }

        // ---- stage 4 pairs into swizzled LDS (<=2-way = free) ----
        {
            paircvt cv;
            cv.u = m0.x; *wp0 = cv.v;
            cv.u = m0.z; *wp1 = cv.v;
            cv.u = m1.x; *wp2 = cv.v;
            cv.u = m1.z; *wp3 = cv.v;
        }
        // RAW barrier #1: order only the LDS staging (lgkmcnt), NOT vmcnt.
        asm volatile("s_waitcnt lgkmcnt(0)" ::: "memory");
        __builtin_amdgcn_s_barrier();

        // ---- read this lane's 16 pairs (cols [32L, 32L+32)) ----
        h2 hv[16];
#pragma unroll
        for (int k = 0; k < 16; ++k)
            hv[k] = *rp[k];

        // ---- 8 rows x 32 cols of dot product per lane ----
        float p[8] = {0.f, 0.f, 0.f, 0.f, 0.f, 0.f, 0.f, 0.f};
#pragma unroll
        for (int r = 0; r < 8; ++r)
#pragma unroll
            for (int k = 0; k < 16; ++k)
                p[r] = fdot2f(wreg[r][k], hv[k], p[r]);

        // ---- merge-reduce, dims {1,2,8} on VALU; d=4 pure-reduce on DS ----
        const bool h1 = (L & 1), h2b = (L & 2), h8 = (L & 8);
        float v0, v1, v2, v3;
        {
            float k0 = h1 ? p[1] : p[0], s0 = h1 ? p[0] : p[1];
            v0 = k0 + dpp_xor1(s0);
            float k1 = h1 ? p[3] : p[2], s1 = h1 ? p[2] : p[3];
            v1 = k1 + dpp_xor1(s1);
            float k2 = h1 ? p[5] : p[4], s2 = h1 ? p[4] : p[5];
            v2 = k2 + dpp_xor1(s2);
            float k3 = h1 ? p[7] : p[6], s3 = h1 ? p[6] : p[7];
            v3 = k3 + dpp_xor1(s3);
        }
        float w0, w1;
        {
            float k0 = h2b ? v1 : v0, s0 = h2b ? v0 : v1;
            w0 = k0 + dpp_xor2(s0);
            float k1 = h2b ? v3 : v2, s1 = h2b ? v2 : v3;
            w1 = k1 + dpp_xor2(s1);
        }
        float tot;
        {
            float k0 = h8 ? w1 : w0, s0 = h8 ? w0 : w1;
            tot = k0 + dpp_ror8(s0);          // d=8 merge on VALU
        }
        tot += __shfl_xor(tot, 4, 64);        // d=4 pure reduction (DS)
        tot = xor16_add(tot);
        tot = xor32_add(tot);
        tot += xp;

        // ---- gates: width-16 gathers from lanes {(L&8)+r} ----
        const int ub8 = L & 8;   // 0 -> unit0 rows on lanes 0..3, 8 -> unit1
        float gi = __shfl(tot, ub8 + 0, 16);
        float gf = __shfl(tot, ub8 + 1, 16);
        float gg = __shfl(tot, ub8 + 2, 16);
        float go = __shfl(tot, ub8 + 3, 16);
        float ii = sigmoid_f(gi);
        float ff = sigmoid_f(gf);
        float g  = tanh_f(gg);
        float oo = sigmoid_f(go);
        c = ff * c + ii * g;
        float h = oo * tanh_f(c);

        // ---- publish, per-block coalesced ----
        const unsigned pout = (t + 1) & 1;
        {
            float hA = __shfl(h, 0, 16);  // unit ubase   (sublane 0)
            float hB = __shfl(h, 8, 16);  // unit ubase+1 (sublane 8)
            paircvt pk;
            pk.v.x = (_Float16)hA;
            pk.v.y = (_Float16)hB;
            unsigned long long msg =
                ((unsigned long long)(t + 1) << 32) | (unsigned long long)pk.u;
            if (L == 0) pkbuf[w] = msg;    // deposit wave's message
        }
        // barrier #2: gather the 4 messages (lgkm-only, raw)
        asm volatile("s_waitcnt lgkmcnt(0)" ::: "memory");
        __builtin_amdgcn_s_barrier();
        if (w == 0) {
            // lanes 0..31: replica r = L>>2, slot b*4 + (L&3).
            // 4 adjacent lanes per replica hit contiguous u64s -> one
            // coalesced 32B transaction per replica (8 total).
            unsigned long long m = pkbuf[L & 3];
            if (L < 32)
                __hip_atomic_store(
                    &hrep[((size_t)(L >> 2) * 2 + pout) * NSLOT
                          + (size_t)b * 4 + (L & 3)], m,
                    __ATOMIC_RELAXED, __HIP_MEMORY_SCOPE_AGENT);
        } else if (w == 1) {
            // non-critical history write: lanes 0..3, coalesced 16B
            if (L < 4)
                ((unsigned*)hs16)[(size_t)t * (HD / 2) + b * 4 + L] =
                    (unsigned)pkbuf[L];
        }
        pubclk = __builtin_amdgcn_s_memrealtime();
    }
}

// Output projection: out[t,0:3] = hs[t]·W_uvw^T + b_uvw,
//                    out[t,3:6] = hs[t]·W_pqr^T + b_pqr
__global__ __launch_bounds__(256) void out_proj_kernel(
    const _Float16* __restrict__ hs16,
    const float* __restrict__ W_uvw, const float* __restrict__ b_uvw,
    const float* __restrict__ W_pqr, const float* __restrict__ b_pqr,
    float* __restrict__ out)
{
    __shared__ float Ws[6 * HD];
    const int tid = threadIdx.x;
    for (int i = tid; i < 3 * HD; i += 256) Ws[i] = W_uvw[i];
    for (int i = tid; i < 3 * HD; i += 256) Ws[3 * HD + i] = W_pqr[i];
    __syncthreads();

    const int w = tid >> 6, L = tid & 63;
#pragma unroll
    for (int r = 0; r < 4; ++r) {
        const int t = blockIdx.x * 16 + w * 4 + r;
        const _Float16* hrow = hs16 + (size_t)t * HD;
        float acc[6] = {0.f, 0.f, 0.f, 0.f, 0.f, 0.f};
        for (int cidx = L; cidx < HD; cidx += 64) {
            float hval = (float)hrow[cidx];
#pragma unroll
            for (int j = 0; j < 6; ++j) acc[j] += hval * Ws[j * HD + cidx];
        }
#pragma unroll
        for (int j = 0; j < 6; ++j) {
#pragma unroll
            for (int d = 1; d < 64; d <<= 1)
                acc[j] += __shfl_xor(acc[j], d, 64);
        }
        if (L == 0) {
#pragma unroll
            for (int j = 0; j < 6; ++j)
                out[(size_t)t * 6 + j] =
                    acc[j] + (j < 3 ? b_uvw[j] : b_pqr[j - 3]);
        }
    }
}

extern "C" void kernel_launch(void* const* d_in, const int* in_sizes, int n_in,
                              void* d_out, int out_size, void* d_ws, size_t ws_size,
                              hipStream_t stream) {
    (void)in_sizes; (void)n_in; (void)out_size; (void)ws_size;

    const float* sa    = (const float*)d_in[0];
    const float* W_ih  = (const float*)d_in[1];
    const float* W_hh  = (const float*)d_in[2];
    const float* b_ih  = (const float*)d_in[3];
    const float* b_hh  = (const float*)d_in[4];
    const float* W_uvw = (const float*)d_in[5];
    const float* b_uvw = (const float*)d_in[6];
    const float* W_pqr = (const float*)d_in[7];
    const float* b_pqr = (const float*)d_in[8];
    float* out = (float*)d_out;

    // workspace: [hs16: 32 MB][hrep: NXCD*2*NSLOT*8 = 128 KB]
    char* ws = (char*)d_ws;
    _Float16* hs16 = (_Float16*)ws;
    unsigned long long* hrep =
        (unsigned long long*)(ws + (size_t)SEQ * HD * 2);

    // zero replicas: tag 0 == "h_0 = 0 is ready" in every copy
    hipMemsetAsync(hrep, 0, (size_t)NXCD * 2 * NSLOT * 8, stream);

    hipLaunchKernelGGL(lstm_persist, dim3(NBLK), dim3(NTHR), 0, stream,
                       sa, W_ih, W_hh, b_ih, b_hh, hrep, hs16);
    hipLaunchKernelGGL(out_proj_kernel, dim3(SEQ / 16), dim3(256), 0, stream,
                       hs16, W_uvw, b_uvw, W_pqr, b_pqr, out);
}

// Round 10
// 13457.364 us; speedup vs baseline: 1.1567x; 1.0185x over previous
//
#include <hip/hip_runtime.h>
#include <cstdint>
#include <cstddef>

#define SEQ   8192
#define HD    2048
#define IND   16
#define NBLK  256   // one block per CU; each owns 8 hidden units
#define NTHR  256   // 4 waves; wave w owns units {b*8+2w, b*8+2w+1} = 8 rows
#define NSLOT 1024  // u64 slots per parity: lo32 = 2xfp16 h-pair, hi32 = tag
#define NXCD  8

// Gate: R14 showed 14 vs 24 ticks neutral -> T_vis ~850-1300cy; keep 16.
#define GATE_TICKS 16ull

typedef _Float16 h2  __attribute__((ext_vector_type(2)));
typedef unsigned u32x4 __attribute__((ext_vector_type(4)));

union paircvt { h2 v; unsigned u; };

__device__ __forceinline__ float fdot2f(h2 a, h2 b, float c) {
#if defined(__has_builtin)
#if __has_builtin(__builtin_amdgcn_fdot2)
    return __builtin_amdgcn_fdot2(a, b, c, false);
#else
    return c + (float)a.x * (float)b.x + (float)a.y * (float)b.y;
#endif
#else
    return c + (float)a.x * (float)b.x + (float)a.y * (float)b.y;
#endif
}

__device__ __forceinline__ float sigmoid_f(float x) {
    return 1.f / (1.f + __expf(-x));
}
__device__ __forceinline__ float tanh_f(float x) {
    float e = __expf(2.f * x);
    return 1.f - 2.f / (e + 1.f);
}

__device__ __forceinline__ unsigned my_xcd() {
    unsigned x;
    asm volatile("s_getreg_b32 %0, hwreg(HW_REG_XCC_ID, 0, 4)" : "=s"(x));
    return x & (NXCD - 1);
}

// ---- VALU cross-lane primitives (replace DS-pipe shuffles) ----
__device__ __forceinline__ float dpp_xor1(float x) {
    int i = __builtin_bit_cast(int, x);
    int r = __builtin_amdgcn_mov_dpp(i, 0xB1, 0xf, 0xf, false); // [1,0,3,2]
    return __builtin_bit_cast(float, r);
}
__device__ __forceinline__ float dpp_xor2(float x) {
    int i = __builtin_bit_cast(int, x);
    int r = __builtin_amdgcn_mov_dpp(i, 0x4E, 0xf, 0xf, false); // [2,3,0,1]
    return __builtin_bit_cast(float, r);
}
// row_ror:8 (ctrl 0x128): within each 16-lane row, dest L reads (L+8)&15,
// which equals L^8 -- an exact xor-8 exchange on the VALU pipe.
__device__ __forceinline__ float dpp_ror8(float x) {
    int i = __builtin_bit_cast(int, x);
    int r = __builtin_amdgcn_mov_dpp(i, 0x128, 0xf, 0xf, false);
    return __builtin_bit_cast(float, r);
}
__device__ __forceinline__ float xor16_add(float x) {
    float a = x, b = x;
    asm volatile("v_permlane16_swap_b32 %0, %1" : "+v"(a), "+v"(b));
    return a + b;
}
__device__ __forceinline__ float xor32_add(float x) {
    float a = x, b = x;
    asm volatile("v_permlane32_swap_b32 %0, %1" : "+v"(a), "+v"(b));
    return a + b;
}

// Persistent LSTM, round 19: publish-tail trims on top of R18 (13.71ms,
// WRITE_SIZE 2.16GB->590MB confirmed the store-RMW theory).
// Three same-class changes, everything else byte-identical to R18:
//  (1) DPP pack: hO = dpp_ror8(h) replaces the two width-16 h-broadcast
//      shuffles (lane0 holds unit0 h, lane8 holds unit1 h; row_ror:8
//      moves lane8 -> lane0 on the VALU pipe). -2 serial DS ops.
//  (2) replica stores split across waves 0 AND 1 (4 x 32B transactions
//      each, lanes 0..15): halves the agent-scope store-ack queue any
//      single wave must drain at its next poll's vmcnt(0) (in-order
//      vmcnt retirement catches own stores), and issues the burst in
//      parallel from two waves.
//  (3) s_setprio(1) around the store section of waves 0/1 (publisher
//      waves are the block-critical path).
// hs16 history moves to wave 2. h values/conversions identical -> absmax
// exactly 2.441e-4.
__global__ __launch_bounds__(NTHR, 1) void lstm_persist(
    const float* __restrict__ sa,    // [SEQ, IND]
    const float* __restrict__ W_ih,  // [4*HD, IND]
    const float* __restrict__ W_hh,  // [4*HD, HD]
    const float* __restrict__ b_ih,  // [4*HD]
    const float* __restrict__ b_hh,  // [4*HD]
    unsigned long long* __restrict__ hrep,  // [NXCD][2][NSLOT] replicas
    _Float16* __restrict__ hs16)     // [SEQ, HD] h history (fp16)
{
    const int b   = blockIdx.x;
    const int tid = threadIdx.x;
    const int w   = tid >> 6;        // wave 0..3
    const int L   = tid & 63;        // lane
    const unsigned xcd = my_xcd();

    __shared__ h2 hh2[16 * 64];      // h_t pairs, XOR-swizzled [k][row^2k]
    __shared__ unsigned long long pkbuf[4];   // per-wave packed messages

    const int ubase = b * 8 + 2 * w; // first of this wave's 2 units

    // ---- one-time: W_hh fragment -> registers (fp16 pairs) ----
    h2 wreg[8][16];
#pragma unroll
    for (int r = 0; r < 8; ++r) {
        const int row = (r & 3) * HD + ubase + (r >> 2);
        const float4* Wr = (const float4*)(W_hh + (size_t)row * HD + L * 32);
#pragma unroll
        for (int q = 0; q < 8; ++q) {
            float4 f = Wr[q];
            h2 lo; lo.x = (_Float16)f.x; lo.y = (_Float16)f.y;
            h2 hi; hi.x = (_Float16)f.z; hi.y = (_Float16)f.w;
            wreg[r][2 * q]     = lo;
            wreg[r][2 * q + 1] = hi;
        }
    }
    // W_ih row + bias; row map (R17): gate = L&3, unit = (L>>3)&1
    const int rowL = (L & 3) * HD + ubase + ((L >> 3) & 1);
    float wih[IND];
    {
        const float4* Wi = (const float4*)(W_ih + (size_t)rowL * IND);
#pragma unroll
        for (int q = 0; q < 4; ++q) {
            float4 f = Wi[q];
            wih[4 * q]     = f.x;
            wih[4 * q + 1] = f.y;
            wih[4 * q + 2] = f.z;
            wih[4 * q + 3] = f.w;
        }
    }
    const float bias = b_ih[rowL] + b_hh[rowL];

    // ---- hoisted LDS addresses (loop-invariant swizzle math) ----
    h2* wp0; h2* wp1; h2* wp2; h2* wp3;
    {
        const int pa = 2 * tid, pb = 2 * tid + 1;
        const int pc = 512 + 2 * tid, pd = 513 + 2 * tid;
        wp0 = &hh2[(pa & 15) * 64 + (((pa >> 4) ^ (2 * (pa & 15))) & 63)];
        wp1 = &hh2[(pb & 15) * 64 + (((pb >> 4) ^ (2 * (pb & 15))) & 63)];
        wp2 = &hh2[(pc & 15) * 64 + (((pc >> 4) ^ (2 * (pc & 15))) & 63)];
        wp3 = &hh2[(pd & 15) * 64 + (((pd >> 4) ^ (2 * (pd & 15))) & 63)];
    }
    const h2* rp[16];
#pragma unroll
    for (int k = 0; k < 16; ++k)
        rp[k] = &hh2[k * 64 + ((L ^ (2 * k)) & 63)];

    // x_t prefetch registers (depth 1)
    float sat[IND];
    {
        const float4* s4 = (const float4*)(sa);
#pragma unroll
        for (int q = 0; q < 4; ++q) {
            float4 f = s4[q];
            sat[4 * q]     = f.x;
            sat[4 * q + 1] = f.y;
            sat[4 * q + 2] = f.z;
            sat[4 * q + 3] = f.w;
        }
    }

    // cell state: lanes with (L&8)==0 hold c of unit0, (L&8)==8 -> unit1
    float c = 0.f;
    unsigned long long pubclk = 0;

    for (unsigned t = 0; t < SEQ; ++t) {
        // ---- xp from prefetched x_t (no serial load stall) ----
        float xp = bias;
#pragma unroll
        for (int k = 0; k < IND; ++k) xp += sat[k] * wih[k];

        // ---- issue x_{t+1} prefetch PRE-GATE: retires under gate+poll ----
        if (t + 1 < SEQ) {
            const float4* s4 = (const float4*)(sa + (size_t)(t + 1) * IND);
#pragma unroll
            for (int q = 0; q < 4; ++q) {
                float4 f = s4[q];
                sat[4 * q]     = f.x;
                sat[4 * q + 1] = f.y;
                sat[4 * q + 2] = f.z;
                sat[4 * q + 3] = f.w;
            }
        }

        // ---- clock gate: no LLC polls before own-publish + min flight ----
        if (t) {
            unsigned long long now;
            do {
                now = __builtin_amdgcn_s_memrealtime();
            } while (now - pubclk < GATE_TICKS);
        }

        // ---- staggered double-buffered poll of own-XCD replica ----
        const unsigned pin = t & 1;
        const uint32_t* base =
            (const uint32_t*)(hrep + ((size_t)xcd * 2 + pin) * NSLOT);
        const uint32_t* pp0 = base + 4 * tid;
        const uint32_t* pp1 = base + 1024 + 4 * tid;
        u32x4 m0, m1, n0, n1;
        asm volatile("s_waitcnt vmcnt(0)" ::: "memory");
        asm volatile(
            "global_load_dwordx4 %0, %2, off sc1\n\t"
            "global_load_dwordx4 %1, %3, off sc1"
            : "=v"(m0), "=v"(m1) : "v"(pp0), "v"(pp1) : "memory");
        int tries = 0;
        for (;;) {
            asm volatile(
                "global_load_dwordx4 %0, %2, off sc1\n\t"
                "global_load_dwordx4 %1, %3, off sc1"
                : "=v"(n0), "=v"(n1) : "v"(pp0), "v"(pp1) : "memory");
            asm volatile("s_waitcnt vmcnt(2)"
                         : "+v"(m0), "+v"(m1) :: "memory");
            if ((m0.y == t) & (m0.w == t) & (m1.y == t) & (m1.w == t))
                break;
            asm volatile(
                "global_load_dwordx4 %0, %2, off sc1\n\t"
                "global_load_dwordx4 %1, %3, off sc1"
                : "=v"(m0), "=v"(m1) : "v"(pp0), "v"(pp1) : "memory");
            asm volatile("s_waitcnt vmcnt(2)"
                         : "+v"(n0), "+v"(n1) :: "memory");
            if ((n0.y == t) & (n0.w == t) & (n1.y == t) & (n1.w == t)) {
                m0 = n0; m1 = n1;
                break;
            }
            if (++tries > 8) __builtin_amdgcn_s_sleep(1);
        }

        // ---- stage 4 pairs into swizzled LDS (<=2-way = free) ----
        {
            paircvt cv;
            cv.u = m0.x; *wp0 = cv.v;
            cv.u = m0.z; *wp1 = cv.v;
            cv.u = m1.x; *wp2 = cv.v;
            cv.u = m1.z; *wp3 = cv.v;
        }
        // RAW barrier #1: order only the LDS staging (lgkmcnt), NOT vmcnt.
        asm volatile("s_waitcnt lgkmcnt(0)" ::: "memory");
        __builtin_amdgcn_s_barrier();

        // ---- read this lane's 16 pairs (cols [32L, 32L+32)) ----
        h2 hv[16];
#pragma unroll
        for (int k = 0; k < 16; ++k)
            hv[k] = *rp[k];

        // ---- 8 rows x 32 cols of dot product per lane ----
        float p[8] = {0.f, 0.f, 0.f, 0.f, 0.f, 0.f, 0.f, 0.f};
#pragma unroll
        for (int r = 0; r < 8; ++r)
#pragma unroll
            for (int k = 0; k < 16; ++k)
                p[r] = fdot2f(wreg[r][k], hv[k], p[r]);

        // ---- merge-reduce, dims {1,2,8} on VALU; d=4 pure-reduce on DS ----
        const bool h1 = (L & 1), h2b = (L & 2), h8 = (L & 8);
        float v0, v1, v2, v3;
        {
            float k0 = h1 ? p[1] : p[0], s0 = h1 ? p[0] : p[1];
            v0 = k0 + dpp_xor1(s0);
            float k1 = h1 ? p[3] : p[2], s1 = h1 ? p[2] : p[3];
            v1 = k1 + dpp_xor1(s1);
            float k2 = h1 ? p[5] : p[4], s2 = h1 ? p[4] : p[5];
            v2 = k2 + dpp_xor1(s2);
            float k3 = h1 ? p[7] : p[6], s3 = h1 ? p[6] : p[7];
            v3 = k3 + dpp_xor1(s3);
        }
        float w0, w1;
        {
            float k0 = h2b ? v1 : v0, s0 = h2b ? v0 : v1;
            w0 = k0 + dpp_xor2(s0);
            float k1 = h2b ? v3 : v2, s1 = h2b ? v2 : v3;
            w1 = k1 + dpp_xor2(s1);
        }
        float tot;
        {
            float k0 = h8 ? w1 : w0, s0 = h8 ? w0 : w1;
            tot = k0 + dpp_ror8(s0);          // d=8 merge on VALU
        }
        tot += __shfl_xor(tot, 4, 64);        // d=4 pure reduction (DS)
        tot = xor16_add(tot);
        tot = xor32_add(tot);
        tot += xp;

        // ---- gates: width-16 gathers from lanes {(L&8)+r} ----
        const int ub8 = L & 8;   // 0 -> unit0 rows on lanes 0..3, 8 -> unit1
        float gi = __shfl(tot, ub8 + 0, 16);
        float gf = __shfl(tot, ub8 + 1, 16);
        float gg = __shfl(tot, ub8 + 2, 16);
        float go = __shfl(tot, ub8 + 3, 16);
        float ii = sigmoid_f(gi);
        float ff = sigmoid_f(gf);
        float g  = tanh_f(gg);
        float oo = sigmoid_f(go);
        c = ff * c + ii * g;
        float h = oo * tanh_f(c);

        // ---- pack via DPP (no DS): lane0 has unit0 h; ror8 brings unit1 ----
        const unsigned pout = (t + 1) & 1;
        {
            float hO = dpp_ror8(h);       // lane 0 <- lane 8's h (unit1)
            paircvt pk;
            pk.v.x = (_Float16)h;         // valid on lane 0 (unit ubase)
            pk.v.y = (_Float16)hO;        // unit ubase+1
            unsigned long long msg =
                ((unsigned long long)(t + 1) << 32) | (unsigned long long)pk.u;
            if (L == 0) pkbuf[w] = msg;   // deposit wave's message
        }
        // barrier #2: gather the 4 messages (lgkm-only, raw)
        asm volatile("s_waitcnt lgkmcnt(0)" ::: "memory");
        __builtin_amdgcn_s_barrier();
        if (w < 2) {
            // wave w stores replicas 4w..4w+3; lanes 0..15: replica
            // 4w+(L>>2), slot b*4+(L&3). 4 adjacent lanes per replica =
            // one coalesced 32B transaction (4 per wave, 8 total).
            __builtin_amdgcn_s_setprio(1);
            unsigned long long m = pkbuf[L & 3];
            if (L < 16)
                __hip_atomic_store(
                    &hrep[((size_t)(4 * w + (L >> 2)) * 2 + pout) * NSLOT
                          + (size_t)b * 4 + (L & 3)], m,
                    __ATOMIC_RELAXED, __HIP_MEMORY_SCOPE_AGENT);
            __builtin_amdgcn_s_setprio(0);
        } else if (w == 2) {
            // non-critical history write: lanes 0..3, coalesced 16B
            if (L < 4)
                ((unsigned*)hs16)[(size_t)t * (HD / 2) + b * 4 + L] =
                    (unsigned)pkbuf[L];
        }
        pubclk = __builtin_amdgcn_s_memrealtime();
    }
}

// Output projection: out[t,0:3] = hs[t]·W_uvw^T + b_uvw,
//                    out[t,3:6] = hs[t]·W_pqr^T + b_pqr
__global__ __launch_bounds__(256) void out_proj_kernel(
    const _Float16* __restrict__ hs16,
    const float* __restrict__ W_uvw, const float* __restrict__ b_uvw,
    const float* __restrict__ W_pqr, const float* __restrict__ b_pqr,
    float* __restrict__ out)
{
    __shared__ float Ws[6 * HD];
    const int tid = threadIdx.x;
    for (int i = tid; i < 3 * HD; i += 256) Ws[i] = W_uvw[i];
    for (int i = tid; i < 3 * HD; i += 256) Ws[3 * HD + i] = W_pqr[i];
    __syncthreads();

    const int w = tid >> 6, L = tid & 63;
#pragma unroll
    for (int r = 0; r < 4; ++r) {
        const int t = blockIdx.x * 16 + w * 4 + r;
        const _Float16* hrow = hs16 + (size_t)t * HD;
        float acc[6] = {0.f, 0.f, 0.f, 0.f, 0.f, 0.f};
        for (int cidx = L; cidx < HD; cidx += 64) {
            float hval = (float)hrow[cidx];
#pragma unroll
            for (int j = 0; j < 6; ++j) acc[j] += hval * Ws[j * HD + cidx];
        }
#pragma unroll
        for (int j = 0; j < 6; ++j) {
#pragma unroll
            for (int d = 1; d < 64; d <<= 1)
                acc[j] += __shfl_xor(acc[j], d, 64);
        }
        if (L == 0) {
#pragma unroll
            for (int j = 0; j < 6; ++j)
                out[(size_t)t * 6 + j] =
                    acc[j] + (j < 3 ? b_uvw[j] : b_pqr[j - 3]);
        }
    }
}

extern "C" void kernel_launch(void* const* d_in, const int* in_sizes, int n_in,
                              void* d_out, int out_size, void* d_ws, size_t ws_size,
                              hipStream_t stream) {
    (void)in_sizes; (void)n_in; (void)out_size; (void)ws_size;

    const float* sa    = (const float*)d_in[0];
    const float* W_ih  = (const float*)d_in[1];
    const float* W_hh  = (const float*)d_in[2];
    const float* b_ih  = (const float*)d_in[3];
    const float* b_hh  = (const float*)d_in[4];
    const float* W_uvw = (const float*)d_in[5];
    const float* b_uvw = (const float*)d_in[6];
    const float* W_pqr = (const float*)d_in[7];
    const float* b_pqr = (const float*)d_in[8];
    float* out = (float*)d_out;

    // workspace: [hs16: 32 MB][hrep: NXCD*2*NSLOT*8 = 128 KB]
    char* ws = (char*)d_ws;
    _Float16* hs16 = (_Float16*)ws;
    unsigned long long* hrep =
        (unsigned long long*)(ws + (size_t)SEQ * HD * 2);

    // zero replicas: tag 0 == "h_0 = 0 is ready" in every copy
    hipMemsetAsync(hrep, 0, (size_t)NXCD * 2 * NSLOT * 8, stream);

    hipLaunchKernelGGL(lstm_persist, dim3(NBLK), dim3(NTHR), 0, stream,
                       sa, W_ih, W_hh, b_ih, b_hh, hrep, hs16);
    hipLaunchKernelGGL(out_proj_kernel, dim3(SEQ / 16), dim3(256), 0, stream,
                       hs16, W_uvw, b_uvw, W_pqr, b_pqr, out);
}